// Round 10
// baseline (74.836 us; speedup 1.0000x reference)
//
#include <hip/hip_runtime.h>

typedef float f32x2 __attribute__((ext_vector_type(2)));
typedef float f32x4 __attribute__((ext_vector_type(4)));
typedef short short8 __attribute__((ext_vector_type(8)));  // 8 x bf16 bits

static __device__ __forceinline__ unsigned short f2bf(float f) {
    __bf16 h = (__bf16)f;
    return __builtin_bit_cast(unsigned short, h);
}

// ---------------------------------------------------------------------------
// Kernel A: contract TT cores into dense TRANSPOSED bf16 weights.
//   WdT[j][pos(i)] = Wd[i][j]  (pos = k-slot permutation matching gemm1's
//   dense x load pattern; dot products are slot-permutation invariant).
//   WuT[d][k] = Wu[k][d].
// ---------------------------------------------------------------------------
__global__ __launch_bounds__(256) void tt_build_w_kernel(
    const float* __restrict__ d1, const float* __restrict__ d2, const float* __restrict__ d3,
    const float* __restrict__ u1, const float* __restrict__ u2, const float* __restrict__ u3,
    unsigned short* __restrict__ WdT, unsigned short* __restrict__ WuT)
{
    int t = blockIdx.x * 256 + threadIdx.x;
    if (t < 65536) {
        int j = t >> 10, i = t & 1023;
        int i1 = i >> 7, i2 = (i >> 3) & 15, i3 = i & 7;
        int j1 = j >> 4, j2 = (j >> 2) & 3, j3 = j & 3;
        float t3[8];
#pragma unroll
        for (int b = 0; b < 8; ++b) t3[b] = d3[(b * 8 + i3) * 4 + j3];
        float wsum = 0.f;
#pragma unroll
        for (int a = 0; a < 8; ++a) {
            float va = d1[(i1 * 4 + j1) * 8 + a];
            const float* p2 = d2 + ((a * 16 + i2) * 4 + j2) * 8;
            float wa = 0.f;
#pragma unroll
            for (int b = 0; b < 8; ++b) wa = fmaf(p2[b], t3[b], wa);
            wsum = fmaf(va, wa, wsum);
        }
        int g = i & 31;
        int h = g >> 4, kgg = (g >> 2) & 3, e = g & 3;
        int pos = (i & ~31) | (kgg * 8 + h * 4 + e);
        WdT[j * 1024 + pos] = f2bf(wsum);
    } else {
        int t2 = t - 65536;
        int d = t2 >> 6, k = t2 & 63;
        int k1 = k >> 4, k2 = (k >> 2) & 3, k3 = k & 3;
        int o1 = d >> 7, o2 = (d >> 3) & 15, o3 = d & 7;
        float t3[8];
#pragma unroll
        for (int b = 0; b < 8; ++b) t3[b] = u3[(b * 4 + k3) * 8 + o3];
        float wsum = 0.f;
#pragma unroll
        for (int a = 0; a < 8; ++a) {
            float va = u1[(k1 * 8 + o1) * 8 + a];
            const float* p2 = u2 + ((a * 4 + k2) * 16 + o2) * 8;
            float wa = 0.f;
#pragma unroll
            for (int b = 0; b < 8; ++b) wa = fmaf(p2[b], t3[b], wa);
            wsum = fmaf(va, wa, wsum);
        }
        WuT[d * 64 + k] = f2bf(wsum);
    }
}

// asm burst: 16 pinned global_load_dwordx4, dense 64B sectors per row
#define XBURST(dst, ptr)                                                                     \
    do {                                                                                     \
        asm volatile("global_load_dwordx4 %0, %1, off offset:0"   : "=v"(dst[0])  : "v"(ptr) : "memory"); \
        asm volatile("global_load_dwordx4 %0, %1, off offset:64"  : "=v"(dst[1])  : "v"(ptr) : "memory"); \
        asm volatile("global_load_dwordx4 %0, %1, off offset:128" : "=v"(dst[2])  : "v"(ptr) : "memory"); \
        asm volatile("global_load_dwordx4 %0, %1, off offset:192" : "=v"(dst[3])  : "v"(ptr) : "memory"); \
        asm volatile("global_load_dwordx4 %0, %1, off offset:256" : "=v"(dst[4])  : "v"(ptr) : "memory"); \
        asm volatile("global_load_dwordx4 %0, %1, off offset:320" : "=v"(dst[5])  : "v"(ptr) : "memory"); \
        asm volatile("global_load_dwordx4 %0, %1, off offset:384" : "=v"(dst[6])  : "v"(ptr) : "memory"); \
        asm volatile("global_load_dwordx4 %0, %1, off offset:448" : "=v"(dst[7])  : "v"(ptr) : "memory"); \
        asm volatile("global_load_dwordx4 %0, %1, off offset:512" : "=v"(dst[8])  : "v"(ptr) : "memory"); \
        asm volatile("global_load_dwordx4 %0, %1, off offset:576" : "=v"(dst[9])  : "v"(ptr) : "memory"); \
        asm volatile("global_load_dwordx4 %0, %1, off offset:640" : "=v"(dst[10]) : "v"(ptr) : "memory"); \
        asm volatile("global_load_dwordx4 %0, %1, off offset:704" : "=v"(dst[11]) : "v"(ptr) : "memory"); \
        asm volatile("global_load_dwordx4 %0, %1, off offset:768" : "=v"(dst[12]) : "v"(ptr) : "memory"); \
        asm volatile("global_load_dwordx4 %0, %1, off offset:832" : "=v"(dst[13]) : "v"(ptr) : "memory"); \
        asm volatile("global_load_dwordx4 %0, %1, off offset:896" : "=v"(dst[14]) : "v"(ptr) : "memory"); \
        asm volatile("global_load_dwordx4 %0, %1, off offset:960" : "=v"(dst[15]) : "v"(ptr) : "memory"); \
    } while (0)

static __device__ __forceinline__ void mfma_ktile(
    const f32x4 (&xs)[16], const unsigned short* __restrict__ wp, f32x4 (&acc)[4])
{
#pragma unroll
    for (int ks = 0; ks < 8; ++ks) {
        short8 b0 = *reinterpret_cast<const short8*>(wp + 0 * 16384 + ks * 32);
        short8 b1 = *reinterpret_cast<const short8*>(wp + 1 * 16384 + ks * 32);
        short8 b2 = *reinterpret_cast<const short8*>(wp + 2 * 16384 + ks * 32);
        short8 b3 = *reinterpret_cast<const short8*>(wp + 3 * 16384 + ks * 32);
        union { short8 v; unsigned short e[8]; } a;
        a.e[0] = f2bf(xs[2 * ks][0]); a.e[1] = f2bf(xs[2 * ks][1]);
        a.e[2] = f2bf(xs[2 * ks][2]); a.e[3] = f2bf(xs[2 * ks][3]);
        a.e[4] = f2bf(xs[2 * ks + 1][0]); a.e[5] = f2bf(xs[2 * ks + 1][1]);
        a.e[6] = f2bf(xs[2 * ks + 1][2]); a.e[7] = f2bf(xs[2 * ks + 1][3]);
        acc[0] = __builtin_amdgcn_mfma_f32_16x16x32_bf16(a.v, b0, acc[0], 0, 0, 0);
        acc[1] = __builtin_amdgcn_mfma_f32_16x16x32_bf16(a.v, b1, acc[1], 0, 0, 0);
        acc[2] = __builtin_amdgcn_mfma_f32_16x16x32_bf16(a.v, b2, acc[2], 0, 0, 0);
        acc[3] = __builtin_amdgcn_mfma_f32_16x16x32_bf16(a.v, b3, acc[3], 0, 0, 0);
    }
}

// ---------------------------------------------------------------------------
// K1: z = relu(x @ Wd + bd) -> zbuf. (unchanged from r9; launched TWICE this
// round as an idempotent A/B timing probe: dur_delta vs r9 == gemm1 time)
// ---------------------------------------------------------------------------
__global__ __launch_bounds__(256, 4) void tt_gemm1_kernel(
    const float* __restrict__ x, const unsigned short* __restrict__ WdT,
    const float* __restrict__ bd, unsigned short* __restrict__ zbuf)
{
    __shared__ float red[4][1024];
    const int t = threadIdx.x;
    const int lane = t & 63;
    const int w = t >> 6;
    const int l15 = lane & 15;
    const int kg = lane >> 4;
    const int kb = w * 256;
    const int tile = blockIdx.x;

    const float* xp = x + (size_t)(tile * 16 + l15) * 1024 + kb + kg * 4;
    f32x4 xs[16];
    XBURST(xs, xp);

    const int colz = (t >> 6) * 16 + (t & 15);
    const int rowz = ((t & 63) >> 4) * 4;
    const float bdv = bd[colz];
    const unsigned short* wp = WdT + l15 * 1024 + kb + kg * 8;

    asm volatile("s_waitcnt vmcnt(0)" ::: "memory");
    __builtin_amdgcn_sched_barrier(0);
    f32x4 acc[4] = {{0.f, 0.f, 0.f, 0.f}, {0.f, 0.f, 0.f, 0.f},
                    {0.f, 0.f, 0.f, 0.f}, {0.f, 0.f, 0.f, 0.f}};
    mfma_ktile(xs, wp, acc);

#pragma unroll
    for (int ct = 0; ct < 4; ++ct)
        *reinterpret_cast<f32x4*>(&red[w][ct * 256 + lane * 4]) = acc[ct];
    __syncthreads();
    {
        f32x4 v0 = *reinterpret_cast<const f32x4*>(&red[0][t * 4]);
        f32x4 v1 = *reinterpret_cast<const f32x4*>(&red[1][t * 4]);
        f32x4 v2 = *reinterpret_cast<const f32x4*>(&red[2][t * 4]);
        f32x4 v3 = *reinterpret_cast<const f32x4*>(&red[3][t * 4]);
#pragma unroll
        for (int r = 0; r < 4; ++r) {
            float zz = v0[r] + v1[r] + v2[r] + v3[r] + bdv;
            zz = zz > 0.f ? zz : 0.f;
            zbuf[tile * 1024 + (rowz + r) * 64 + colz] = f2bf(zz);
        }
    }
}

// ---------------------------------------------------------------------------
// K2: y = z @ Wu + bu (unchanged from r9)
// ---------------------------------------------------------------------------
__global__ __launch_bounds__(256) void tt_gemm2_kernel(
    const unsigned short* __restrict__ zbuf, const unsigned short* __restrict__ WuT,
    const float* __restrict__ bu, float* __restrict__ y)
{
    __shared__ unsigned short wlds[512 * 64];   // 64 KB
    const int t = threadIdx.x;
    const int lane = t & 63;
    const int w = t >> 6;
    const int l15 = lane & 15;
    const int kg = lane >> 4;
    const int ch = blockIdx.x & 1;
    const int rg = blockIdx.x >> 1;

    const unsigned short* src = WuT + ch * 512 * 64;
#pragma unroll
    for (int i = 0; i < 16; ++i) {
        int idx = i * 256 + t;
        int dst = idx ^ ((idx >> 3) & 7);
        *reinterpret_cast<short8*>(&wlds[dst * 8]) =
            *reinterpret_cast<const short8*>(src + idx * 8);
    }
    f32x4 bv[8];
#pragma unroll
    for (int i = 0; i < 8; ++i)
        bv[i] = *reinterpret_cast<const f32x4*>(bu + ch * 512 + w * 128 + i * 16 + kg * 4);
    __syncthreads();

#pragma unroll
    for (int tt = 0; tt < 4; ++tt) {
        const int tile = rg * 4 + tt;
        short8 az0 = *reinterpret_cast<const short8*>(zbuf + tile * 1024 + l15 * 64 + kg * 8);
        short8 az1 = *reinterpret_cast<const short8*>(zbuf + tile * 1024 + l15 * 64 + 32 + kg * 8);
        const size_t yb = (size_t)(tile * 16 + l15) * 1024 + ch * 512 + w * 128;
#pragma unroll
        for (int i = 0; i < 8; ++i) {
            const int row = w * 128 + i * 16 + l15;
            const int s = row & 7;
            short8 b0 = *reinterpret_cast<const short8*>(&wlds[(row * 8 + (kg ^ s)) * 8]);
            short8 b1 = *reinterpret_cast<const short8*>(&wlds[(row * 8 + ((kg + 4) ^ s)) * 8]);
            f32x4 c = {0.f, 0.f, 0.f, 0.f};
            c = __builtin_amdgcn_mfma_f32_16x16x32_bf16(b0, az0, c, 0, 0, 0);
            c = __builtin_amdgcn_mfma_f32_16x16x32_bf16(b1, az1, c, 0, 0, 0);
            f32x4 o;
#pragma unroll
            for (int r = 0; r < 4; ++r) o[r] = c[r] + bv[i][r];
            *reinterpret_cast<f32x4*>(y + yb + i * 16 + kg * 4) = o;
        }
    }
}

extern "C" void kernel_launch(void* const* d_in, const int* in_sizes, int n_in,
                              void* d_out, int out_size, void* d_ws, size_t ws_size,
                              hipStream_t stream) {
    const float* x  = (const float*)d_in[0];
    const float* d1 = (const float*)d_in[1];
    const float* d2 = (const float*)d_in[2];
    const float* d3 = (const float*)d_in[3];
    const float* u1 = (const float*)d_in[4];
    const float* u2 = (const float*)d_in[5];
    const float* u3 = (const float*)d_in[6];
    const float* bd = (const float*)d_in[7];
    const float* bu = (const float*)d_in[8];
    float* y = (float*)d_out;
    unsigned short* WdT  = (unsigned short*)d_ws;   // 64x1024 bf16 (128 KB)
    unsigned short* WuT  = WdT + 65536;             // 1024x64 bf16 (128 KB)
    unsigned short* zbuf = WuT + 65536;             // 1024 tiles x 16 x 64 bf16 (2 MB)

    hipLaunchKernelGGL(tt_build_w_kernel, dim3(512), dim3(256), 0, stream,
                       d1, d2, d3, u1, u2, u3, WdT, WuT);
    // A/B timing probe: gemm1 launched twice (idempotent). dur_us delta vs
    // round 9 (~51 us) isolates gemm1's duration.
    hipLaunchKernelGGL(tt_gemm1_kernel, dim3(1024), dim3(256), 0, stream,
                       x, WdT, bd, zbuf);
    hipLaunchKernelGGL(tt_gemm1_kernel, dim3(1024), dim3(256), 0, stream,
                       x, WdT, bd, zbuf);
    hipLaunchKernelGGL(tt_gemm2_kernel, dim3(512), dim3(256), 0, stream,
                       zbuf, WuT, bu, y);
}

// Round 11
// 55.210 us; speedup vs baseline: 1.3555x; 1.3555x over previous
//
#include <hip/hip_runtime.h>

typedef float f32x2 __attribute__((ext_vector_type(2)));
typedef float f32x4 __attribute__((ext_vector_type(4)));
typedef short short8 __attribute__((ext_vector_type(8)));  // 8 x bf16 bits

static __device__ __forceinline__ unsigned short f2bf(float f) {
    __bf16 h = (__bf16)f;
    return __builtin_bit_cast(unsigned short, h);
}

// ---------------------------------------------------------------------------
// Kernel A: contract TT cores into dense TRANSPOSED bf16 weights.
//   WdT[j][pos(i)] = Wd[i][j]  (pos = k-slot permutation matching gemm1's
//   dense x load pattern; dot products are slot-permutation invariant).
//   WuT[d][k] = Wu[k][d].
// ---------------------------------------------------------------------------
__global__ __launch_bounds__(256) void tt_build_w_kernel(
    const float* __restrict__ d1, const float* __restrict__ d2, const float* __restrict__ d3,
    const float* __restrict__ u1, const float* __restrict__ u2, const float* __restrict__ u3,
    unsigned short* __restrict__ WdT, unsigned short* __restrict__ WuT)
{
    int t = blockIdx.x * 256 + threadIdx.x;
    if (t < 65536) {
        int j = t >> 10, i = t & 1023;
        int i1 = i >> 7, i2 = (i >> 3) & 15, i3 = i & 7;
        int j1 = j >> 4, j2 = (j >> 2) & 3, j3 = j & 3;
        float t3[8];
#pragma unroll
        for (int b = 0; b < 8; ++b) t3[b] = d3[(b * 8 + i3) * 4 + j3];
        float wsum = 0.f;
#pragma unroll
        for (int a = 0; a < 8; ++a) {
            float va = d1[(i1 * 4 + j1) * 8 + a];
            const float* p2 = d2 + ((a * 16 + i2) * 4 + j2) * 8;
            float wa = 0.f;
#pragma unroll
            for (int b = 0; b < 8; ++b) wa = fmaf(p2[b], t3[b], wa);
            wsum = fmaf(va, wa, wsum);
        }
        int g = i & 31;
        int h = g >> 4, kgg = (g >> 2) & 3, e = g & 3;
        int pos = (i & ~31) | (kgg * 8 + h * 4 + e);
        WdT[j * 1024 + pos] = f2bf(wsum);
    } else {
        int t2 = t - 65536;
        int d = t2 >> 6, k = t2 & 63;
        int k1 = k >> 4, k2 = (k >> 2) & 3, k3 = k & 3;
        int o1 = d >> 7, o2 = (d >> 3) & 15, o3 = d & 7;
        float t3[8];
#pragma unroll
        for (int b = 0; b < 8; ++b) t3[b] = u3[(b * 4 + k3) * 8 + o3];
        float wsum = 0.f;
#pragma unroll
        for (int a = 0; a < 8; ++a) {
            float va = u1[(k1 * 8 + o1) * 8 + a];
            const float* p2 = u2 + ((a * 4 + k2) * 16 + o2) * 8;
            float wa = 0.f;
#pragma unroll
            for (int b = 0; b < 8; ++b) wa = fmaf(p2[b], t3[b], wa);
            wsum = fmaf(va, wa, wsum);
        }
        WuT[d * 64 + k] = f2bf(wsum);
    }
}

// ---------------------------------------------------------------------------
// K1: z = relu(x @ Wd + bd) -> zbuf[tile][m16][j64].
// 1024 blocks x 512 thr (8 waves, K-split 8: wave w owns k in [128w,+128)).
// ALL global loads are one pinned asm burst in FIFO order:
//   xs[0..7] (x, 8 KB/wave) then wd[ks][ct] ks-major (16 loads, WdT/L2).
// MFMA stages gated by counted s_waitcnt vmcnt(12/8/4/0): stage k needs the
// oldest 12+4k ops (all xs + wd through ks=k) -> x and WdT drain CONCURRENTLY
// and compute starts as soon as the needed prefix lands (r9 serialized:
// full x drain, then a compiler-paced WdT chain => 24us measured by r10 probe).
// ---------------------------------------------------------------------------
__global__ __launch_bounds__(512, 4) void tt_gemm1_kernel(
    const float* __restrict__ x, const unsigned short* __restrict__ WdT,
    const float* __restrict__ bd, unsigned short* __restrict__ zbuf)
{
    __shared__ float red[8][1024];
    const int t = threadIdx.x;
    const int lane = t & 63;
    const int w = t >> 6;          // 0..7
    const int l15 = lane & 15;
    const int kg = lane >> 4;
    const int kb = w * 128;
    const int tile = blockIdx.x;

    // reduce-phase constants + bd preload (before asm: oldest VMEM, harmless)
    const int e0 = t * 2;
    const int ctr = e0 >> 8, rem = e0 & 255;
    const int jz = ctr * 16 + ((rem >> 2) & 15);
    const int m0 = (rem >> 6) * 4 + (e0 & 3);
    const float bdj = bd[jz];

    const float* xp = x + (size_t)(tile * 16 + l15) * 1024 + kb + kg * 4;
    const unsigned short* wp0 = WdT + l15 * 1024 + kb + kg * 8;
    const unsigned short* wp1 = wp0 + 16 * 1024;
    const unsigned short* wp2 = wp0 + 32 * 1024;
    const unsigned short* wp3 = wp0 + 48 * 1024;

    f32x4 xs[8];
    short8 wd0[4], wd1[4], wd2[4], wd3[4];

#define XB(i, off) asm volatile("global_load_dwordx4 %0, %1, off offset:" #off \
                                : "=v"(xs[i]) : "v"(xp) : "memory")
    XB(0, 0); XB(1, 64); XB(2, 128); XB(3, 192);
    XB(4, 256); XB(5, 320); XB(6, 384); XB(7, 448);
#undef XB
#define WD(ks, off)                                                                               \
    asm volatile("global_load_dwordx4 %0, %1, off offset:" #off : "=v"(wd0[ks]) : "v"(wp0) : "memory"); \
    asm volatile("global_load_dwordx4 %0, %1, off offset:" #off : "=v"(wd1[ks]) : "v"(wp1) : "memory"); \
    asm volatile("global_load_dwordx4 %0, %1, off offset:" #off : "=v"(wd2[ks]) : "v"(wp2) : "memory"); \
    asm volatile("global_load_dwordx4 %0, %1, off offset:" #off : "=v"(wd3[ks]) : "v"(wp3) : "memory");
    WD(0, 0) WD(1, 64) WD(2, 128) WD(3, 192)
#undef WD

    f32x4 acc[4] = {{0.f, 0.f, 0.f, 0.f}, {0.f, 0.f, 0.f, 0.f},
                    {0.f, 0.f, 0.f, 0.f}, {0.f, 0.f, 0.f, 0.f}};
#define G1STAGE(ks, NWAIT) do {                                                      \
    asm volatile("s_waitcnt vmcnt(" #NWAIT ")" ::: "memory");                        \
    __builtin_amdgcn_sched_barrier(0);                                               \
    union { short8 v; unsigned short e[8]; } a;                                      \
    a.e[0] = f2bf(xs[2 * ks][0]);     a.e[1] = f2bf(xs[2 * ks][1]);                  \
    a.e[2] = f2bf(xs[2 * ks][2]);     a.e[3] = f2bf(xs[2 * ks][3]);                  \
    a.e[4] = f2bf(xs[2 * ks + 1][0]); a.e[5] = f2bf(xs[2 * ks + 1][1]);              \
    a.e[6] = f2bf(xs[2 * ks + 1][2]); a.e[7] = f2bf(xs[2 * ks + 1][3]);              \
    acc[0] = __builtin_amdgcn_mfma_f32_16x16x32_bf16(a.v, wd0[ks], acc[0], 0, 0, 0); \
    acc[1] = __builtin_amdgcn_mfma_f32_16x16x32_bf16(a.v, wd1[ks], acc[1], 0, 0, 0); \
    acc[2] = __builtin_amdgcn_mfma_f32_16x16x32_bf16(a.v, wd2[ks], acc[2], 0, 0, 0); \
    acc[3] = __builtin_amdgcn_mfma_f32_16x16x32_bf16(a.v, wd3[ks], acc[3], 0, 0, 0); \
} while (0)
    G1STAGE(0, 12);
    G1STAGE(1, 8);
    G1STAGE(2, 4);
    G1STAGE(3, 0);
#undef G1STAGE

    // lane holds z-partial[m=kg*4+r][j=ct*16+l15]; conflict-free b128 writes
#pragma unroll
    for (int ct = 0; ct < 4; ++ct)
        *reinterpret_cast<f32x4*>(&red[w][ct * 256 + lane * 4]) = acc[ct];
    __syncthreads();

    // 8-way reduce + bias + relu -> zbuf (thread t: elements e0, e0+1)
    {
        float s0 = 0.f, s1 = 0.f;
#pragma unroll
        for (int ww = 0; ww < 8; ++ww) {
            f32x2 v = *reinterpret_cast<const f32x2*>(&red[ww][e0]);
            s0 += v[0]; s1 += v[1];
        }
        s0 += bdj; s1 += bdj;
        s0 = s0 > 0.f ? s0 : 0.f;
        s1 = s1 > 0.f ? s1 : 0.f;
        zbuf[tile * 1024 + m0 * 64 + jz] = f2bf(s0);
        zbuf[tile * 1024 + (m0 + 1) * 64 + jz] = f2bf(s1);
    }
}

// ---------------------------------------------------------------------------
// K2: y = z @ Wu + bu. Pure write-stream, NO LDS (WuT is L2-resident and each
// wave needs only 8 fragments -> hold in registers; r9's 64KB LDS staging was
// overhead and capped occupancy at 2 blocks/CU). Block = 64 rows x 256 cols:
// ch = blockIdx>>8 (col quarter), rg = blockIdx&255 (4 tiles) so consecutive
// blocks share z tiles within an XCD. Wave w owns 64 cols; z prefetched one
// tile ahead; dwordx4 stores fire-and-forget.
// ---------------------------------------------------------------------------
__global__ __launch_bounds__(256, 4) void tt_gemm2_kernel(
    const unsigned short* __restrict__ zbuf, const unsigned short* __restrict__ WuT,
    const float* __restrict__ bu, float* __restrict__ y)
{
    const int t = threadIdx.x;
    const int lane = t & 63;
    const int w = t >> 6;
    const int l15 = lane & 15;
    const int kg = lane >> 4;
    const int ch = blockIdx.x >> 8;    // 0..3
    const int rg = blockIdx.x & 255;   // 0..255
    const int cb = ch * 256 + w * 64;

    short8 wa[8];
    f32x4 bv[4];
#pragma unroll
    for (int i = 0; i < 4; ++i) {
        const unsigned short* wup = WuT + (cb + i * 16 + l15) * 64 + kg * 8;
        wa[2 * i]     = *reinterpret_cast<const short8*>(wup);
        wa[2 * i + 1] = *reinterpret_cast<const short8*>(wup + 32);
        bv[i] = *reinterpret_cast<const f32x4*>(bu + cb + i * 16 + kg * 4);
    }

    const int tile0 = rg * 4;
    const unsigned short* zp = zbuf + tile0 * 1024 + l15 * 64 + kg * 8;
    short8 az0 = *reinterpret_cast<const short8*>(zp);
    short8 az1 = *reinterpret_cast<const short8*>(zp + 32);
#pragma unroll
    for (int tt = 0; tt < 4; ++tt) {
        short8 nz0, nz1;
        if (tt < 3) {
            nz0 = *reinterpret_cast<const short8*>(zp + (tt + 1) * 1024);
            nz1 = *reinterpret_cast<const short8*>(zp + (tt + 1) * 1024 + 32);
        }
        const size_t yb = (size_t)((tile0 + tt) * 16 + l15) * 1024 + cb;
#pragma unroll
        for (int i = 0; i < 4; ++i) {
            f32x4 c = {0.f, 0.f, 0.f, 0.f};
            c = __builtin_amdgcn_mfma_f32_16x16x32_bf16(wa[2 * i], az0, c, 0, 0, 0);
            c = __builtin_amdgcn_mfma_f32_16x16x32_bf16(wa[2 * i + 1], az1, c, 0, 0, 0);
            f32x4 o;
#pragma unroll
            for (int r = 0; r < 4; ++r) o[r] = c[r] + bv[i][r];
            // lane holds y[tile*16+l15][cb + i*16 + kg*4 + r]
            *reinterpret_cast<f32x4*>(y + yb + i * 16 + kg * 4) = o;
        }
        if (tt < 3) { az0 = nz0; az1 = nz1; }
    }
}

extern "C" void kernel_launch(void* const* d_in, const int* in_sizes, int n_in,
                              void* d_out, int out_size, void* d_ws, size_t ws_size,
                              hipStream_t stream) {
    const float* x  = (const float*)d_in[0];
    const float* d1 = (const float*)d_in[1];
    const float* d2 = (const float*)d_in[2];
    const float* d3 = (const float*)d_in[3];
    const float* u1 = (const float*)d_in[4];
    const float* u2 = (const float*)d_in[5];
    const float* u3 = (const float*)d_in[6];
    const float* bd = (const float*)d_in[7];
    const float* bu = (const float*)d_in[8];
    float* y = (float*)d_out;
    unsigned short* WdT  = (unsigned short*)d_ws;   // 64x1024 bf16 (128 KB)
    unsigned short* WuT  = WdT + 65536;             // 1024x64 bf16 (128 KB)
    unsigned short* zbuf = WuT + 65536;             // 1024 tiles x 16 x 64 bf16 (2 MB)

    hipLaunchKernelGGL(tt_build_w_kernel, dim3(512), dim3(256), 0, stream,
                       d1, d2, d3, u1, u2, u3, WdT, WuT);
    hipLaunchKernelGGL(tt_gemm1_kernel, dim3(1024), dim3(512), 0, stream,
                       x, WdT, bd, zbuf);
    hipLaunchKernelGGL(tt_gemm2_kernel, dim3(1024), dim3(256), 0, stream,
                       zbuf, WuT, bu, y);
}